// Round 3
// baseline (1371.738 us; speedup 1.0000x reference)
//
#include <hip/hip_runtime.h>
#include <stdint.h>

// EdgeNetwork per-edge MLP — ALL float32 (reference dtypes; rounds 1-2 NaN'd
// because f32 data was misread as bf16).
//   x = [nf[src], nf[dst], edge_attr]  (144 f32)
//   h1 = lrelu(LN(x @ W1 + b1)); h2 = lrelu(LN(h1 @ W2 + b2)); out = h2 @ W3 + b3
// edge_index: reference is int64, harness doc says int32 — sniffed on device.

#define TPB 128
#define NEG_SLOPE 0.1f
#define LN_EPS    1e-5f

// Single LDS float buffer, two phases:
//  phase A: W1 [0,9216) | b1 [9216) | g1 [9280) | be1 [9344)   (9408 floats)
//  phase B: h  [0,8192)  (h[k*TPB+tid], 128 thr x 64 f32)
//           W2 [9408,13504) | W3 [13504) | b2 [13568) | g2 [13632)
//           be2 [13696) | b3 [13760]
#define A_W1   0
#define A_B1   9216
#define A_G1   9280
#define A_BE1  9344
#define B_H    0
#define B_W2   9408
#define B_W3   13504
#define B_B2   13568
#define B_G2   13632
#define B_BE2  13696
#define B_B3   13760
#define LDS_FLOATS 13764   // 53.8 KB -> 3 blocks/CU from the 160 KB pool

__global__ __launch_bounds__(TPB)
void edge_mlp_f32(const float* __restrict__ nf, const int* __restrict__ ei,
                  const float* __restrict__ ea,
                  const float* __restrict__ W1, const float* __restrict__ b1,
                  const float* __restrict__ g1, const float* __restrict__ be1,
                  const float* __restrict__ W2, const float* __restrict__ b2,
                  const float* __restrict__ g2, const float* __restrict__ be2,
                  const float* __restrict__ W3, const float* __restrict__ b3,
                  float* __restrict__ out, int E) {
  __shared__ __align__(16) float L[LDS_FLOATS];
  __shared__ int idx64;

  const int tid = threadIdx.x;
  int e = blockIdx.x * TPB + tid;
  const bool valid = (e < E);
  if (!valid) e = 0;  // clamp; store is guarded, barriers stay uniform

  // ---- int64-vs-int32 sniff (wave 0): int64 indices < 2^31 have zero high
  // words at every odd int32 slot; genuine int32 indices essentially never do.
  if (tid < 64) {
    int v = ei[2 * tid + 1];
    unsigned long long b = __ballot(v == 0);
    if (tid == 0) idx64 = (b == 0xFFFFFFFFFFFFFFFFull) ? 1 : 0;
  }

  // ---- Phase A staging: W1 + b1/g1/be1 (f32, float4 copies) ----
  for (int i = tid; i < 2304; i += TPB)               // 9216 floats
    ((float4*)(L + A_W1))[i] = ((const float4*)W1)[i];
  if (tid < 16)       ((float4*)(L + A_B1))[tid]       = ((const float4*)b1)[tid];
  else if (tid < 32)  ((float4*)(L + A_G1))[tid - 16]  = ((const float4*)g1)[tid - 16];
  else if (tid < 48)  ((float4*)(L + A_BE1))[tid - 32] = ((const float4*)be1)[tid - 32];
  __syncthreads();

  // ---- Index fetch (wave-uniform branch on sniffed dtype) ----
  int s, d;
  if (idx64) { s = ei[2 * e]; d = ei[2 * (E + e)]; }   // low words of int64
  else       { s = ei[e];     d = ei[E + e]; }

  const float4* ps = (const float4*)(nf + (size_t)s * 64);  // 16 chunks
  const float4* pd = (const float4*)(nf + (size_t)d * 64);  // 16 chunks
  const float4* pa = (const float4*)(ea + (size_t)e * 16);  // 4 chunks

  // ---- Layer 1: acc[j] = b1[j] + sum_k x[k] * W1[k][j] ----
  float acc[64];
  #pragma unroll
  for (int j = 0; j < 64; ++j) acc[j] = L[A_B1 + j];

  float4 cur = ps[0];
  #pragma unroll 1
  for (int t = 0; t < 36; ++t) {
    const int tn = t + 1;                    // +1 chunk prefetch
    float4 nxt = cur;
    if (tn < 16)      nxt = ps[tn];
    else if (tn < 32) nxt = pd[tn - 16];
    else if (tn < 36) nxt = pa[tn - 32];
    const float xv[4] = {cur.x, cur.y, cur.z, cur.w};
    #pragma unroll
    for (int kk = 0; kk < 4; ++kk) {
      const float4* wr = (const float4*)(L + (4 * t + kk) * 64);
      #pragma unroll
      for (int q = 0; q < 16; ++q) {
        float4 w = wr[q];
        acc[4 * q + 0] = fmaf(xv[kk], w.x, acc[4 * q + 0]);
        acc[4 * q + 1] = fmaf(xv[kk], w.y, acc[4 * q + 1]);
        acc[4 * q + 2] = fmaf(xv[kk], w.z, acc[4 * q + 2]);
        acc[4 * q + 3] = fmaf(xv[kk], w.w, acc[4 * q + 3]);
      }
    }
    cur = nxt;
  }

  // ---- LN1 + LeakyReLU (in registers) ----
  {
    float sum = 0.f, sq = 0.f;
    #pragma unroll
    for (int j = 0; j < 64; ++j) { sum += acc[j]; sq = fmaf(acc[j], acc[j], sq); }
    float mu  = sum * (1.f / 64.f);
    float var = sq * (1.f / 64.f) - mu * mu;
    float rs  = rsqrtf(var + LN_EPS);
    #pragma unroll
    for (int j = 0; j < 64; ++j) {
      float h = (acc[j] - mu) * rs * L[A_G1 + j] + L[A_BE1 + j];
      acc[j] = h >= 0.f ? h : NEG_SLOPE * h;
    }
  }
  __syncthreads();   // everyone done reading phase-A weights

  // ---- Write h (f32) + stage phase B ----
  #pragma unroll
  for (int k = 0; k < 64; ++k) L[B_H + k * TPB + tid] = acc[k];
  for (int i = tid; i < 1024; i += TPB)               // W2: 4096 floats
    ((float4*)(L + B_W2))[i] = ((const float4*)W2)[i];
  if (tid < 16)       ((float4*)(L + B_W3))[tid]       = ((const float4*)W3)[tid];
  else if (tid < 32)  ((float4*)(L + B_B2))[tid - 16]  = ((const float4*)b2)[tid - 16];
  else if (tid < 48)  ((float4*)(L + B_G2))[tid - 32]  = ((const float4*)g2)[tid - 32];
  else if (tid < 64)  ((float4*)(L + B_BE2))[tid - 48] = ((const float4*)be2)[tid - 48];
  else if (tid == 64) L[B_B3] = b3[0];
  __syncthreads();

  // ---- Layer 2: acc2[j] = b2[j] + sum_k h[k] * W2[k][j] ----
  float acc2[64];
  #pragma unroll
  for (int j = 0; j < 64; ++j) acc2[j] = L[B_B2 + j];

  #pragma unroll 2
  for (int k = 0; k < 64; ++k) {
    float hv = L[B_H + k * TPB + tid];       // uniform k: 2 lanes/bank, free
    const float4* wr = (const float4*)(L + B_W2 + k * 64);
    #pragma unroll
    for (int q = 0; q < 16; ++q) {
      float4 w = wr[q];
      acc2[4 * q + 0] = fmaf(hv, w.x, acc2[4 * q + 0]);
      acc2[4 * q + 1] = fmaf(hv, w.y, acc2[4 * q + 1]);
      acc2[4 * q + 2] = fmaf(hv, w.z, acc2[4 * q + 2]);
      acc2[4 * q + 3] = fmaf(hv, w.w, acc2[4 * q + 3]);
    }
  }

  // ---- LN2 + LeakyReLU + Layer 3 ----
  {
    float sum = 0.f, sq = 0.f;
    #pragma unroll
    for (int j = 0; j < 64; ++j) { sum += acc2[j]; sq = fmaf(acc2[j], acc2[j], sq); }
    float mu  = sum * (1.f / 64.f);
    float var = sq * (1.f / 64.f) - mu * mu;
    float rs  = rsqrtf(var + LN_EPS);
    float o = L[B_B3];
    #pragma unroll
    for (int j = 0; j < 64; ++j) {
      float h = (acc2[j] - mu) * rs * L[B_G2 + j] + L[B_BE2 + j];
      h = h >= 0.f ? h : NEG_SLOPE * h;
      o = fmaf(h, L[B_W3 + j], o);
    }
    if (valid) out[e] = o;
  }
}

extern "C" void kernel_launch(void* const* d_in, const int* in_sizes, int n_in,
                              void* d_out, int out_size, void* d_ws, size_t ws_size,
                              hipStream_t stream) {
  const float* nf = (const float*)d_in[0];   // node_features (f32, 50000x64)
  const int*   ei = (const int*)d_in[1];     // edge_index (int, 2xE)
  const float* ea = (const float*)d_in[2];   // edge_attr (f32, Ex16)

  const int E = out_size;                    // one logit per edge

  edge_mlp_f32<<<(E + TPB - 1) / TPB, TPB, 0, stream>>>(
      nf, ei, ea,
      (const float*)d_in[3],  (const float*)d_in[4],
      (const float*)d_in[5],  (const float*)d_in[6],
      (const float*)d_in[7],  (const float*)d_in[8],
      (const float*)d_in[9],  (const float*)d_in[10],
      (const float*)d_in[11], (const float*)d_in[12],
      (float*)d_out, E);
}

// Round 4
// 1069.632 us; speedup vs baseline: 1.2824x; 1.2824x over previous
//
#include <hip/hip_runtime.h>
#include <stdint.h>

// EdgeNetwork per-edge MLP, all-f32. Round 4: no LDS at all.
// Weights are wave-uniform -> read with uniform addresses from global so the
// compiler promotes them to s_load (SGPR operands to v_fma), freeing the LDS
// pipe and lifting occupancy 1 -> 3 waves/SIMD. h1 stays in registers via a
// fully-unrolled k-loop (static indexing). float2 accumulators to encourage
// v_pk_fma_f32 packing.

#define TPB 256
#define NEG_SLOPE 0.1f
#define LN_EPS    1e-5f

__device__ __forceinline__ void fma2(float a, float wx, float wy, float2& c) {
  c.x = fmaf(a, wx, c.x);
  c.y = fmaf(a, wy, c.y);
}

__global__ __launch_bounds__(TPB, 3)
void edge_mlp(const float* __restrict__ nf, const int* __restrict__ ei,
              const float* __restrict__ ea,
              const float* __restrict__ W1, const float* __restrict__ b1,
              const float* __restrict__ g1, const float* __restrict__ be1,
              const float* __restrict__ W2, const float* __restrict__ b2,
              const float* __restrict__ g2, const float* __restrict__ be2,
              const float* __restrict__ W3, const float* __restrict__ b3,
              float* __restrict__ out, int E) {
  int e = blockIdx.x * TPB + threadIdx.x;
  const bool valid = (e < E);
  if (!valid) e = 0;   // clamp; store is guarded

  // ---- int64-vs-int32 sniff (per-wave ballot, no LDS). int64 indices
  // < 2^31 have all-zero high words at odd int32 slots; random int32
  // indices essentially never do. (Validated: round 3 passed with this.)
  const int lane = threadIdx.x & 63;
  const int hw = ei[2 * lane + 1];
  const bool idx64 = (__ballot(hw == 0) == 0xFFFFFFFFFFFFFFFFull);

  int s, d;
  if (idx64) { s = ei[2 * e]; d = ei[2 * (E + e)]; }   // low words of int64
  else       { s = ei[e];     d = ei[E + e]; }

  const float4* __restrict__ ps = (const float4*)(nf + (size_t)s * 64);  // 16
  const float4* __restrict__ pd = (const float4*)(nf + (size_t)d * 64);  // 16
  const float4* __restrict__ pa = (const float4*)(ea + (size_t)e * 16);  // 4

  // ---- Layer 1: acc[j] = b1[j] + sum_k x[k] * W1[k][j] ----
  float2 acc[32];
  #pragma unroll
  for (int q = 0; q < 16; ++q) {
    float4 b = ((const float4*)b1)[q];       // uniform -> s_load
    acc[2 * q]     = make_float2(b.x, b.y);
    acc[2 * q + 1] = make_float2(b.z, b.w);
  }

  float4 cur = ps[0];
  #pragma unroll 1
  for (int t = 0; t < 36; ++t) {
    const int tn = t + 1;                    // +1 chunk prefetch (uniform branch)
    float4 nxt = cur;
    if (tn < 16)      nxt = ps[tn];
    else if (tn < 32) nxt = pd[tn - 16];
    else if (tn < 36) nxt = pa[tn - 32];
    const float xv[4] = {cur.x, cur.y, cur.z, cur.w};
    const float4* __restrict__ wr = (const float4*)(W1 + t * 256);  // 4 rows
    #pragma unroll
    for (int kk = 0; kk < 4; ++kk) {
      #pragma unroll
      for (int q = 0; q < 16; ++q) {
        float4 w = wr[kk * 16 + q];          // uniform -> s_load
        fma2(xv[kk], w.x, w.y, acc[2 * q]);
        fma2(xv[kk], w.z, w.w, acc[2 * q + 1]);
      }
    }
    cur = nxt;
  }

  // ---- LN1 + LeakyReLU (registers) ----
  {
    float sum = 0.f, sq = 0.f;
    #pragma unroll
    for (int q = 0; q < 32; ++q) {
      sum += acc[q].x + acc[q].y;
      sq = fmaf(acc[q].x, acc[q].x, sq);
      sq = fmaf(acc[q].y, acc[q].y, sq);
    }
    float mu  = sum * (1.f / 64.f);
    float var = sq * (1.f / 64.f) - mu * mu;
    float rs  = rsqrtf(var + LN_EPS);
    #pragma unroll
    for (int q = 0; q < 16; ++q) {
      float4 g  = ((const float4*)g1)[q];    // uniform -> s_load
      float4 be = ((const float4*)be1)[q];
      float h;
      h = (acc[2*q].x   - mu) * rs * g.x + be.x; acc[2*q].x   = h >= 0.f ? h : NEG_SLOPE * h;
      h = (acc[2*q].y   - mu) * rs * g.y + be.y; acc[2*q].y   = h >= 0.f ? h : NEG_SLOPE * h;
      h = (acc[2*q+1].x - mu) * rs * g.z + be.z; acc[2*q+1].x = h >= 0.f ? h : NEG_SLOPE * h;
      h = (acc[2*q+1].y - mu) * rs * g.w + be.w; acc[2*q+1].y = h >= 0.f ? h : NEG_SLOPE * h;
    }
  }

  // ---- Layer 2: acc2[j] = b2[j] + sum_k h[k] * W2[k][j] ----
  // h == acc stays in registers; k fully unrolled -> static indexing.
  float2 acc2[32];
  #pragma unroll
  for (int q = 0; q < 16; ++q) {
    float4 b = ((const float4*)b2)[q];       // uniform -> s_load
    acc2[2 * q]     = make_float2(b.x, b.y);
    acc2[2 * q + 1] = make_float2(b.z, b.w);
  }

  #pragma unroll
  for (int kk = 0; kk < 32; ++kk) {
    const float2 hk = acc[kk];
    const float4* __restrict__ r0 = (const float4*)(W2 + (2 * kk) * 64);
    const float4* __restrict__ r1 = (const float4*)(W2 + (2 * kk + 1) * 64);
    #pragma unroll
    for (int q = 0; q < 16; ++q) {
      float4 w0 = r0[q];                     // uniform -> s_load
      float4 w1 = r1[q];
      fma2(hk.x, w0.x, w0.y, acc2[2 * q]);
      fma2(hk.x, w0.z, w0.w, acc2[2 * q + 1]);
      fma2(hk.y, w1.x, w1.y, acc2[2 * q]);
      fma2(hk.y, w1.z, w1.w, acc2[2 * q + 1]);
    }
  }

  // ---- LN2 + LeakyReLU + Layer 3 ----
  {
    float sum = 0.f, sq = 0.f;
    #pragma unroll
    for (int q = 0; q < 32; ++q) {
      sum += acc2[q].x + acc2[q].y;
      sq = fmaf(acc2[q].x, acc2[q].x, sq);
      sq = fmaf(acc2[q].y, acc2[q].y, sq);
    }
    float mu  = sum * (1.f / 64.f);
    float var = sq * (1.f / 64.f) - mu * mu;
    float rs  = rsqrtf(var + LN_EPS);
    float o = b3[0];
    #pragma unroll
    for (int q = 0; q < 16; ++q) {
      float4 g  = ((const float4*)g2)[q];    // uniform -> s_load
      float4 be = ((const float4*)be2)[q];
      float4 w3 = ((const float4*)W3)[q];
      float h;
      h = (acc2[2*q].x   - mu) * rs * g.x + be.x; h = h >= 0.f ? h : NEG_SLOPE * h; o = fmaf(h, w3.x, o);
      h = (acc2[2*q].y   - mu) * rs * g.y + be.y; h = h >= 0.f ? h : NEG_SLOPE * h; o = fmaf(h, w3.y, o);
      h = (acc2[2*q+1].x - mu) * rs * g.z + be.z; h = h >= 0.f ? h : NEG_SLOPE * h; o = fmaf(h, w3.z, o);
      h = (acc2[2*q+1].y - mu) * rs * g.w + be.w; h = h >= 0.f ? h : NEG_SLOPE * h; o = fmaf(h, w3.w, o);
    }
    if (valid) out[e] = o;
  }
}

extern "C" void kernel_launch(void* const* d_in, const int* in_sizes, int n_in,
                              void* d_out, int out_size, void* d_ws, size_t ws_size,
                              hipStream_t stream) {
  const float* nf = (const float*)d_in[0];   // node_features (f32, 50000x64)
  const int*   ei = (const int*)d_in[1];     // edge_index (2xE, int64 sniffed)
  const float* ea = (const float*)d_in[2];   // edge_attr (f32, Ex16)

  const int E = out_size;                    // one logit per edge

  edge_mlp<<<(E + TPB - 1) / TPB, TPB, 0, stream>>>(
      nf, ei, ea,
      (const float*)d_in[3],  (const float*)d_in[4],
      (const float*)d_in[5],  (const float*)d_in[6],
      (const float*)d_in[7],  (const float*)d_in[8],
      (const float*)d_in[9],  (const float*)d_in[10],
      (const float*)d_in[11], (const float*)d_in[12],
      (float*)d_out, E);
}

// Round 5
// 544.609 us; speedup vs baseline: 2.5188x; 1.9640x over previous
//
#include <hip/hip_runtime.h>
#include <stdint.h>

// EdgeNetwork per-edge MLP — round 5: MFMA (bf16 16x16x32) formulation.
// Per wave: 64 edges. A = x rows (gathered, f32->bf16 in-register),
// B = W^T staged once per block in LDS (bf16, padded rows). LN via 16-lane
// shfl_xor butterflies on the D-layout; h1->A-layout via small LDS transpose.

#define TPB 256
#define NEG_SLOPE 0.1f
#define LN_EPS    1e-5f

typedef __attribute__((ext_vector_type(8))) short short8;   // 8 bf16 (4 VGPR)
typedef __attribute__((ext_vector_type(4))) float f32x4;    // 4 f32

__device__ __forceinline__ uint32_t fb(float x) {
  union { float f; uint32_t u; } c; c.f = x; return c.u;
}
// pack 2 f32 -> 2 bf16 (round-half-up) in one v_perm after two adds
__device__ __forceinline__ uint32_t pkbf(float a, float b) {
  return __builtin_amdgcn_perm(fb(b) + 0x8000u, fb(a) + 0x8000u, 0x07060302u);
}
__device__ __forceinline__ short8 cvt8(f32x4 a, f32x4 b) {
  union { short8 s; uint32_t u[4]; } r;
  r.u[0] = pkbf(a[0], a[1]);
  r.u[1] = pkbf(a[2], a[3]);
  r.u[2] = pkbf(b[0], b[1]);
  r.u[3] = pkbf(b[2], b[3]);
  return r.s;
}
__device__ __forceinline__ short bf16rne(float x) {   // staging (one-time)
  uint32_t u = fb(x);
  return (short)((u + 0x7fffu + ((u >> 16) & 1u)) >> 16);
}
// sum f32x4 across the 16 lanes of a quad-group (xor of lane bits 0-3)
__device__ __forceinline__ void redsum16(f32x4& v) {
  #pragma unroll
  for (int off = 1; off < 16; off <<= 1) {
    f32x4 t;
    t[0] = __shfl_xor(v[0], off, 64);
    t[1] = __shfl_xor(v[1], off, 64);
    t[2] = __shfl_xor(v[2], off, 64);
    t[3] = __shfl_xor(v[3], off, 64);
    v += t;
  }
}

__global__ __launch_bounds__(TPB, 3)
void edge_mlp_mfma(const float* __restrict__ nf, const int* __restrict__ ei,
                   const float* __restrict__ ea,
                   const float* __restrict__ W1, const float* __restrict__ b1,
                   const float* __restrict__ g1, const float* __restrict__ be1,
                   const float* __restrict__ W2, const float* __restrict__ b2,
                   const float* __restrict__ g2, const float* __restrict__ be2,
                   const float* __restrict__ W3, const float* __restrict__ b3,
                   float* __restrict__ out, int E, int ntiles) {
  // W1T[n][k]: 64 rows, k 0..159 (144 real + 16 zero-pad), stride 168 (+8 pad:
  // bank stride 84 dwords mod 32 = 20 -> rows spread, ~2-way = free).
  __shared__ short W1T[64 * 168];      // 21504 B
  __shared__ short W2T[64 * 72];       // 9216 B  (stride 72 -> bank stride 4)
  __shared__ short HB[4][16 * 72];     // 9216 B  per-wave h1 tile (16 edges)

  const int tid  = threadIdx.x;
  const int lane = tid & 63;
  const int wv   = tid >> 6;
  const int ln   = lane & 15;
  const int quad = lane >> 4;

  // ---- Stage W1^T, W2^T as bf16 into LDS (coalesced global reads) ----
  for (int i = tid; i < 9216; i += TPB) {
    int n = i & 63, k = i >> 6;
    W1T[n * 168 + k] = bf16rne(W1[k * 64 + n]);
  }
  for (int i = tid; i < 1024; i += TPB) {            // zero-pad k in [144,160)
    int n = i & 63, k = 144 + (i >> 6);
    W1T[n * 168 + k] = 0;
  }
  for (int i = tid; i < 4096; i += TPB) {
    int n = i & 63, k = i >> 6;
    W2T[n * 72 + k] = bf16rne(W2[k * 64 + n]);
  }
  __syncthreads();

  // ---- Per-lane n-indexed params (n = ln + 16*jt), once per kernel ----
  float b1v[4], g1v[4], be1v[4], b2v[4], g2v[4], be2v[4], W3v[4];
  #pragma unroll
  for (int jt = 0; jt < 4; ++jt) {
    int n = ln + 16 * jt;
    b1v[jt] = b1[n];  g1v[jt] = g1[n];  be1v[jt] = be1[n];
    b2v[jt] = b2[n];  g2v[jt] = g2[n];  be2v[jt] = be2[n];
    W3v[jt] = W3[n];
  }
  const float b3s = b3[0];

  // int64-vs-int32 index sniff (validated rounds 3-4)
  const bool idx64 = (__ballot(ei[2 * lane + 1] == 0) == ~0ull);

  // ---- W2 B-fragments -> registers (reused for all tiles/mt) ----
  short8 w2f[2][4];
  #pragma unroll
  for (int t2 = 0; t2 < 2; ++t2)
    #pragma unroll
    for (int jt = 0; jt < 4; ++jt)
      w2f[t2][jt] = *(const short8*)&W2T[(jt * 16 + ln) * 72 + t2 * 32 + quad * 8];

  for (int tile = blockIdx.x; tile < ntiles; tile += gridDim.x) {
    const int ebase = tile * 256 + wv * 64;

    // per-m-tile edge indices (clamped for tail safety)
    int sI[4], dI[4], eC[4];
    #pragma unroll
    for (int mt = 0; mt < 4; ++mt) {
      int el = ebase + mt * 16 + ln;
      int ec = el < E ? el : E - 1;
      eC[mt] = ec;
      if (idx64) { sI[mt] = ei[2 * ec]; dI[mt] = ei[2 * (E + ec)]; }
      else       { sI[mt] = ei[ec];     dI[mt] = ei[E + ec]; }
    }

    // ---- Layer 1: D(16x64 per mt) = X(16x160) @ W1T-frags ----
    f32x4 acc[4][4];                       // [mt][jt]
    #pragma unroll
    for (int mt = 0; mt < 4; ++mt)
      #pragma unroll
      for (int jt = 0; jt < 4; ++jt) acc[mt][jt] = (f32x4)0.f;

    #pragma unroll
    for (int t = 0; t < 5; ++t) {
      short8 a[4];
      #pragma unroll
      for (int mt = 0; mt < 4; ++mt) {
        const float* rp;
        if (t < 2)      rp = nf + (size_t)sI[mt] * 64 + t * 32 + quad * 8;
        else if (t < 4) rp = nf + (size_t)dI[mt] * 64 + (t - 2) * 32 + quad * 8;
        else            rp = ea + (size_t)eC[mt] * 16 + (quad & 1) * 8;
        // k >= 144 lanes load harmless data; W1T rows there are zero.
        f32x4 x0 = *(const f32x4*)rp;
        f32x4 x1 = *(const f32x4*)(rp + 4);
        a[mt] = cvt8(x0, x1);
      }
      #pragma unroll
      for (int jt = 0; jt < 4; ++jt) {
        short8 bfr = *(const short8*)&W1T[(jt * 16 + ln) * 168 + t * 32 + quad * 8];
        #pragma unroll
        for (int mt = 0; mt < 4; ++mt)
          acc[mt][jt] = __builtin_amdgcn_mfma_f32_16x16x32_bf16(
              a[mt], bfr, acc[mt][jt], 0, 0, 0);
      }
    }

    // ---- Per m-tile: LN1 -> h1 -> (LDS transpose) -> Layer 2 -> LN2 -> out
    #pragma unroll
    for (int mt = 0; mt < 4; ++mt) {
      #pragma unroll
      for (int jt = 0; jt < 4; ++jt) acc[mt][jt] += b1v[jt];   // bias pre-LN

      f32x4 sv = acc[mt][0] + acc[mt][1] + acc[mt][2] + acc[mt][3];
      f32x4 qv = acc[mt][0] * acc[mt][0] + acc[mt][1] * acc[mt][1]
               + acc[mt][2] * acc[mt][2] + acc[mt][3] * acc[mt][3];
      redsum16(sv);
      redsum16(qv);
      f32x4 mu  = sv * (1.f / 64.f);
      f32x4 var = qv * (1.f / 64.f) - mu * mu;
      f32x4 rs;
      rs[0] = rsqrtf(var[0] + LN_EPS); rs[1] = rsqrtf(var[1] + LN_EPS);
      rs[2] = rsqrtf(var[2] + LN_EPS); rs[3] = rsqrtf(var[3] + LN_EPS);

      __syncthreads();   // prior mt's HB reads are done everywhere
      #pragma unroll
      for (int jt = 0; jt < 4; ++jt)
        #pragma unroll
        for (int r = 0; r < 4; ++r) {
          float h = (acc[mt][jt][r] - mu[r]) * rs[r] * g1v[jt] + be1v[jt];
          h = h >= 0.f ? h : NEG_SLOPE * h;
          HB[wv][(quad * 4 + r) * 72 + ln + 16 * jt] =
              (short)((fb(h) + 0x8000u) >> 16);
        }
      __syncthreads();   // h tile visible to all lanes of the wave

      // Layer 2: A-frags from HB (lane: edge=ln, k=t2*32+quad*8)
      f32x4 acc2[4];
      #pragma unroll
      for (int jt = 0; jt < 4; ++jt) acc2[jt] = (f32x4)0.f;
      #pragma unroll
      for (int t2 = 0; t2 < 2; ++t2) {
        short8 a2 = *(const short8*)&HB[wv][ln * 72 + t2 * 32 + quad * 8];
        #pragma unroll
        for (int jt = 0; jt < 4; ++jt)
          acc2[jt] = __builtin_amdgcn_mfma_f32_16x16x32_bf16(
              a2, w2f[t2][jt], acc2[jt], 0, 0, 0);
      }

      // LN2 + lrelu + W3 dot
      #pragma unroll
      for (int jt = 0; jt < 4; ++jt) acc2[jt] += b2v[jt];
      f32x4 s2 = acc2[0] + acc2[1] + acc2[2] + acc2[3];
      f32x4 q2 = acc2[0] * acc2[0] + acc2[1] * acc2[1]
               + acc2[2] * acc2[2] + acc2[3] * acc2[3];
      redsum16(s2);
      redsum16(q2);
      f32x4 mu2  = s2 * (1.f / 64.f);
      f32x4 var2 = q2 * (1.f / 64.f) - mu2 * mu2;
      f32x4 rs2;
      rs2[0] = rsqrtf(var2[0] + LN_EPS); rs2[1] = rsqrtf(var2[1] + LN_EPS);
      rs2[2] = rsqrtf(var2[2] + LN_EPS); rs2[3] = rsqrtf(var2[3] + LN_EPS);

      f32x4 po = (f32x4)0.f;
      #pragma unroll
      for (int jt = 0; jt < 4; ++jt)
        #pragma unroll
        for (int r = 0; r < 4; ++r) {
          float h = (acc2[jt][r] - mu2[r]) * rs2[r] * g2v[jt] + be2v[jt];
          h = h >= 0.f ? h : NEG_SLOPE * h;
          po[r] = fmaf(h, W3v[jt], po[r]);
        }
      redsum16(po);       // sum over the 16 lanes -> all lanes hold 4 edge logits

      if (ln < 4) {       // lanes 0-3 of each quad store edges quad*4 + ln
        int e = ebase + mt * 16 + quad * 4 + ln;
        if (e < E) {
          float v = (ln == 0) ? po[0] : (ln == 1) ? po[1] : (ln == 2) ? po[2] : po[3];
          out[e] = v + b3s;
        }
      }
    }
  }
}

extern "C" void kernel_launch(void* const* d_in, const int* in_sizes, int n_in,
                              void* d_out, int out_size, void* d_ws, size_t ws_size,
                              hipStream_t stream) {
  const float* nf = (const float*)d_in[0];
  const int*   ei = (const int*)d_in[1];
  const float* ea = (const float*)d_in[2];

  const int E = out_size;
  const int ntiles = (E + 255) / 256;
  const int blocks = ntiles < 1024 ? ntiles : 1024;

  edge_mlp_mfma<<<blocks, TPB, 0, stream>>>(
      nf, ei, ea,
      (const float*)d_in[3],  (const float*)d_in[4],
      (const float*)d_in[5],  (const float*)d_in[6],
      (const float*)d_in[7],  (const float*)d_in[8],
      (const float*)d_in[9],  (const float*)d_in[10],
      (const float*)d_in[11], (const float*)d_in[12],
      (float*)d_out, E, ntiles);
}

// Round 6
// 359.906 us; speedup vs baseline: 3.8114x; 1.5132x over previous
//
#include <hip/hip_runtime.h>
#include <stdint.h>

// EdgeNetwork per-edge MLP — round 6: MFMA + latency-hiding fixes.
//  vs r5: (a) launch_bounds(256,2) -> no scratch spill (r5: 140 MB spill writes)
//         (b) no per-mt __syncthreads (HB is wave-private; DS is in-order per
//             wave; explicit lgkmcnt(0) between write and read)
//         (c) all 40 gather loads of a tile issued as one batch (MLP)
//         (d) next tile's indices prefetched before the epilogue

#define TPB 256
#define NEG_SLOPE 0.1f
#define LN_EPS    1e-5f

typedef __attribute__((ext_vector_type(8))) short short8;   // 8 bf16 (4 VGPR)
typedef __attribute__((ext_vector_type(4))) float f32x4;    // 4 f32

__device__ __forceinline__ uint32_t fb(float x) {
  union { float f; uint32_t u; } c; c.f = x; return c.u;
}
// pack 2 f32 -> 2 bf16 (round-half-up) in one v_perm after two adds
__device__ __forceinline__ uint32_t pkbf(float a, float b) {
  return __builtin_amdgcn_perm(fb(b) + 0x8000u, fb(a) + 0x8000u, 0x07060302u);
}
__device__ __forceinline__ short8 cvt8(f32x4 a, f32x4 b) {
  union { short8 s; uint32_t u[4]; } r;
  r.u[0] = pkbf(a[0], a[1]);
  r.u[1] = pkbf(a[2], a[3]);
  r.u[2] = pkbf(b[0], b[1]);
  r.u[3] = pkbf(b[2], b[3]);
  return r.s;
}
__device__ __forceinline__ short bf16rne(float x) {   // staging (one-time)
  uint32_t u = fb(x);
  return (short)((u + 0x7fffu + ((u >> 16) & 1u)) >> 16);
}
// sum f32x4 across the 16 lanes of a quad-group (xor of lane bits 0-3)
__device__ __forceinline__ void redsum16(f32x4& v) {
  #pragma unroll
  for (int off = 1; off < 16; off <<= 1) {
    f32x4 t;
    t[0] = __shfl_xor(v[0], off, 64);
    t[1] = __shfl_xor(v[1], off, 64);
    t[2] = __shfl_xor(v[2], off, 64);
    t[3] = __shfl_xor(v[3], off, 64);
    v += t;
  }
}

__global__ __launch_bounds__(TPB, 2)
void edge_mlp_mfma(const float* __restrict__ nf, const int* __restrict__ ei,
                   const float* __restrict__ ea,
                   const float* __restrict__ W1, const float* __restrict__ b1,
                   const float* __restrict__ g1, const float* __restrict__ be1,
                   const float* __restrict__ W2, const float* __restrict__ b2,
                   const float* __restrict__ g2, const float* __restrict__ be2,
                   const float* __restrict__ W3, const float* __restrict__ b3,
                   float* __restrict__ out, int E, int ntiles) {
  __shared__ short W1T[64 * 168];      // [n][k], k 0..159 (144 real + 16 zero)
  __shared__ short W2T[64 * 72];       // [n][k], stride 72
  __shared__ short HB[4][16 * 72];     // per-wave h1 tile (16 edges x 64 + pad)

  const int tid  = threadIdx.x;
  const int lane = tid & 63;
  const int wv   = tid >> 6;
  const int ln   = lane & 15;
  const int quad = lane >> 4;

  // ---- Stage W1^T, W2^T as bf16 into LDS ----
  for (int i = tid; i < 9216; i += TPB) {
    int n = i & 63, k = i >> 6;
    W1T[n * 168 + k] = bf16rne(W1[k * 64 + n]);
  }
  for (int i = tid; i < 1024; i += TPB) {            // zero-pad k in [144,160)
    int n = i & 63, k = 144 + (i >> 6);
    W1T[n * 168 + k] = 0;
  }
  for (int i = tid; i < 4096; i += TPB) {
    int n = i & 63, k = i >> 6;
    W2T[n * 72 + k] = bf16rne(W2[k * 64 + n]);
  }
  __syncthreads();   // the ONLY block barrier

  // ---- Per-lane n-indexed params (n = ln + 16*jt) ----
  float b1v[4], g1v[4], be1v[4], b2v[4], g2v[4], be2v[4], W3v[4];
  #pragma unroll
  for (int jt = 0; jt < 4; ++jt) {
    int n = ln + 16 * jt;
    b1v[jt] = b1[n];  g1v[jt] = g1[n];  be1v[jt] = be1[n];
    b2v[jt] = b2[n];  g2v[jt] = g2[n];  be2v[jt] = be2[n];
    W3v[jt] = W3[n];
  }
  const float b3s = b3[0];

  // int64-vs-int32 index sniff (validated rounds 3-5)
  const bool idx64 = (__ballot(ei[2 * lane + 1] == 0) == ~0ull);

  // ---- Prefetched indices for the first tile ----
  int sI[4], dI[4], eC[4];
  {
    const int ebase = blockIdx.x * 256 + wv * 64;
    #pragma unroll
    for (int mt = 0; mt < 4; ++mt) {
      int el = ebase + mt * 16 + ln;
      int ec = el < E ? el : E - 1;
      eC[mt] = ec;
      if (idx64) { sI[mt] = ei[2 * ec]; dI[mt] = ei[2 * (E + ec)]; }
      else       { sI[mt] = ei[ec];     dI[mt] = ei[E + ec]; }
    }
  }

  for (int tile = blockIdx.x; tile < ntiles; tile += gridDim.x) {
    const int ebase = tile * 256 + wv * 64;

    // ---- Batch gather: all 40 loads issued together, cvt by arrival ----
    short8 afr[4][5];
    #pragma unroll
    for (int mt = 0; mt < 4; ++mt) {
      const float* sp = nf + (size_t)sI[mt] * 64 + quad * 8;
      const float* dp = nf + (size_t)dI[mt] * 64 + quad * 8;
      const float* ap = ea + (size_t)eC[mt] * 16 + (quad & 1) * 8;
      f32x4 c0 = *(const f32x4*)sp;        f32x4 c1 = *(const f32x4*)(sp + 4);
      f32x4 c2 = *(const f32x4*)(sp + 32); f32x4 c3 = *(const f32x4*)(sp + 36);
      f32x4 c4 = *(const f32x4*)dp;        f32x4 c5 = *(const f32x4*)(dp + 4);
      f32x4 c6 = *(const f32x4*)(dp + 32); f32x4 c7 = *(const f32x4*)(dp + 36);
      f32x4 c8 = *(const f32x4*)ap;        f32x4 c9 = *(const f32x4*)(ap + 4);
      afr[mt][0] = cvt8(c0, c1);
      afr[mt][1] = cvt8(c2, c3);
      afr[mt][2] = cvt8(c4, c5);
      afr[mt][3] = cvt8(c6, c7);
      afr[mt][4] = cvt8(c8, c9);   // k>=144 lanes: B rows are zero, value moot
    }

    // ---- Layer 1: 80 MFMAs ----
    f32x4 acc[4][4];                       // [mt][jt]
    #pragma unroll
    for (int mt = 0; mt < 4; ++mt)
      #pragma unroll
      for (int jt = 0; jt < 4; ++jt) acc[mt][jt] = (f32x4)0.f;

    #pragma unroll
    for (int t = 0; t < 5; ++t)
      #pragma unroll
      for (int jt = 0; jt < 4; ++jt) {
        short8 bfr = *(const short8*)&W1T[(jt * 16 + ln) * 168 + t * 32 + quad * 8];
        #pragma unroll
        for (int mt = 0; mt < 4; ++mt)
          acc[mt][jt] = __builtin_amdgcn_mfma_f32_16x16x32_bf16(
              afr[mt][t], bfr, acc[mt][jt], 0, 0, 0);
      }

    // ---- Prefetch next tile's indices (latency hides behind epilogue) ----
    {
      int ntile = tile + gridDim.x;
      if (ntile < ntiles) {
        const int nb = ntile * 256 + wv * 64;
        #pragma unroll
        for (int mt = 0; mt < 4; ++mt) {
          int el = nb + mt * 16 + ln;
          int ec = el < E ? el : E - 1;
          eC[mt] = ec;
          if (idx64) { sI[mt] = ei[2 * ec]; dI[mt] = ei[2 * (E + ec)]; }
          else       { sI[mt] = ei[ec];     dI[mt] = ei[E + ec]; }
        }
      }
    }

    // ---- Epilogue per mt (wave-private, NO block barriers) ----
    #pragma unroll
    for (int mt = 0; mt < 4; ++mt) {
      #pragma unroll
      for (int jt = 0; jt < 4; ++jt) acc[mt][jt] += b1v[jt];

      f32x4 sv = acc[mt][0] + acc[mt][1] + acc[mt][2] + acc[mt][3];
      f32x4 qv = acc[mt][0] * acc[mt][0] + acc[mt][1] * acc[mt][1]
               + acc[mt][2] * acc[mt][2] + acc[mt][3] * acc[mt][3];
      redsum16(sv);
      redsum16(qv);
      f32x4 mu  = sv * (1.f / 64.f);
      f32x4 var = qv * (1.f / 64.f) - mu * mu;
      f32x4 rs;
      rs[0] = rsqrtf(var[0] + LN_EPS); rs[1] = rsqrtf(var[1] + LN_EPS);
      rs[2] = rsqrtf(var[2] + LN_EPS); rs[3] = rsqrtf(var[3] + LN_EPS);

      #pragma unroll
      for (int jt = 0; jt < 4; ++jt)
        #pragma unroll
        for (int r = 0; r < 4; ++r) {
          float h = (acc[mt][jt][r] - mu[r]) * rs[r] * g1v[jt] + be1v[jt];
          h = h >= 0.f ? h : NEG_SLOPE * h;
          HB[wv][(quad * 4 + r) * 72 + ln + 16 * jt] =
              (short)((fb(h) + 0x8000u) >> 16);
        }
      // wave-private handoff: DS is in-order per wave; drain writes then read
      asm volatile("s_waitcnt lgkmcnt(0)" ::: "memory");

      f32x4 acc2[4];
      #pragma unroll
      for (int jt = 0; jt < 4; ++jt) acc2[jt] = (f32x4)0.f;
      #pragma unroll
      for (int t2 = 0; t2 < 2; ++t2) {
        short8 a2 = *(const short8*)&HB[wv][ln * 72 + t2 * 32 + quad * 8];
        #pragma unroll
        for (int jt = 0; jt < 4; ++jt) {
          short8 w2f = *(const short8*)&W2T[(jt * 16 + ln) * 72 + t2 * 32 + quad * 8];
          acc2[jt] = __builtin_amdgcn_mfma_f32_16x16x32_bf16(
              a2, w2f, acc2[jt], 0, 0, 0);
        }
      }

      #pragma unroll
      for (int jt = 0; jt < 4; ++jt) acc2[jt] += b2v[jt];
      f32x4 s2 = acc2[0] + acc2[1] + acc2[2] + acc2[3];
      f32x4 q2 = acc2[0] * acc2[0] + acc2[1] * acc2[1]
               + acc2[2] * acc2[2] + acc2[3] * acc2[3];
      redsum16(s2);
      redsum16(q2);
      f32x4 mu2  = s2 * (1.f / 64.f);
      f32x4 var2 = q2 * (1.f / 64.f) - mu2 * mu2;
      f32x4 rs2;
      rs2[0] = rsqrtf(var2[0] + LN_EPS); rs2[1] = rsqrtf(var2[1] + LN_EPS);
      rs2[2] = rsqrtf(var2[2] + LN_EPS); rs2[3] = rsqrtf(var2[3] + LN_EPS);

      f32x4 po = (f32x4)0.f;
      #pragma unroll
      for (int jt = 0; jt < 4; ++jt)
        #pragma unroll
        for (int r = 0; r < 4; ++r) {
          float h = (acc2[jt][r] - mu2[r]) * rs2[r] * g2v[jt] + be2v[jt];
          h = h >= 0.f ? h : NEG_SLOPE * h;
          po[r] = fmaf(h, W3v[jt], po[r]);
        }
      redsum16(po);

      if (ln < 4) {       // lanes 0-3 of each quad store edges quad*4 + ln
        int e = ebase + mt * 16 + quad * 4 + ln;
        if (e < E) {
          float v = (ln == 0) ? po[0] : (ln == 1) ? po[1] : (ln == 2) ? po[2] : po[3];
          out[e] = v + b3s;
        }
      }
    }
  }
}

extern "C" void kernel_launch(void* const* d_in, const int* in_sizes, int n_in,
                              void* d_out, int out_size, void* d_ws, size_t ws_size,
                              hipStream_t stream) {
  const float* nf = (const float*)d_in[0];
  const int*   ei = (const int*)d_in[1];
  const float* ea = (const float*)d_in[2];

  const int E = out_size;
  const int ntiles = (E + 255) / 256;
  const int blocks = ntiles < 1024 ? ntiles : 1024;

  edge_mlp_mfma<<<blocks, TPB, 0, stream>>>(
      nf, ei, ea,
      (const float*)d_in[3],  (const float*)d_in[4],
      (const float*)d_in[5],  (const float*)d_in[6],
      (const float*)d_in[7],  (const float*)d_in[8],
      (const float*)d_in[9],  (const float*)d_in[10],
      (const float*)d_in[11], (const float*)d_in[12],
      (float*)d_out, E, ntiles);
}

// Round 7
// 324.554 us; speedup vs baseline: 4.2265x; 1.1089x over previous
//
#include <hip/hip_runtime.h>
#include <stdint.h>

// EdgeNetwork per-edge MLP — round 7: DPP epilogue.
//  vs r6: (a) LN reductions via DPP row_ror rotation-allreduce (pure VALU)
//             instead of __shfl_xor (ds_swizzle, LDS pipe) — removes ~320
//             LDS ops + lgkm waits per tile-wave
//         (b) biases folded into accumulator init (D cols depend only on n)
//         (c) leaky-relu as fmax(h, 0.1h)

#define TPB 256
#define NEG_SLOPE 0.1f
#define LN_EPS    1e-5f

typedef __attribute__((ext_vector_type(8))) short short8;   // 8 bf16 (4 VGPR)
typedef __attribute__((ext_vector_type(4))) float f32x4;    // 4 f32

__device__ __forceinline__ uint32_t fb(float x) {
  union { float f; uint32_t u; } c; c.f = x; return c.u;
}
__device__ __forceinline__ float bf(uint32_t x) {
  union { uint32_t u; float f; } c; c.u = x; return c.f;
}
// pack 2 f32 -> 2 bf16 (round-half-up) in one v_perm after two adds
__device__ __forceinline__ uint32_t pkbf(float a, float b) {
  return __builtin_amdgcn_perm(fb(b) + 0x8000u, fb(a) + 0x8000u, 0x07060302u);
}
__device__ __forceinline__ short8 cvt8(f32x4 a, f32x4 b) {
  union { short8 s; uint32_t u[4]; } r;
  r.u[0] = pkbf(a[0], a[1]);
  r.u[1] = pkbf(a[2], a[3]);
  r.u[2] = pkbf(b[0], b[1]);
  r.u[3] = pkbf(b[2], b[3]);
  return r.s;
}
__device__ __forceinline__ short bf16rne(float x) {   // staging (one-time)
  uint32_t u = fb(x);
  return (short)((u + 0x7fffu + ((u >> 16) & 1u)) >> 16);
}

// DPP rotation-allreduce across each row of 16 lanes: v += ror(v,1); ... ror8.
// After 4 steps every lane in the row holds the row sum. Pure VALU.
template <int CTRL>
__device__ __forceinline__ float dppadd(float v) {
  int r = __builtin_amdgcn_update_dpp(0, (int)fb(v), CTRL, 0xf, 0xf, true);
  return v + bf((uint32_t)r);
}
__device__ __forceinline__ float rowsum16(float v) {
  v = dppadd<0x121>(v);   // row_ror:1
  v = dppadd<0x122>(v);   // row_ror:2
  v = dppadd<0x124>(v);   // row_ror:4
  v = dppadd<0x128>(v);   // row_ror:8
  return v;
}
__device__ __forceinline__ void redsum16(f32x4& v) {
  #pragma unroll
  for (int c = 0; c < 4; ++c) v[c] = rowsum16(v[c]);
}

__global__ __launch_bounds__(TPB, 2)
void edge_mlp_mfma(const float* __restrict__ nf, const int* __restrict__ ei,
                   const float* __restrict__ ea,
                   const float* __restrict__ W1, const float* __restrict__ b1,
                   const float* __restrict__ g1, const float* __restrict__ be1,
                   const float* __restrict__ W2, const float* __restrict__ b2,
                   const float* __restrict__ g2, const float* __restrict__ be2,
                   const float* __restrict__ W3, const float* __restrict__ b3,
                   float* __restrict__ out, int E, int ntiles) {
  __shared__ short W1T[64 * 168];      // [n][k], k 0..159 (144 real + 16 zero)
  __shared__ short W2T[64 * 72];       // [n][k], stride 72
  __shared__ short HB[4][16 * 72];     // per-wave h1 tile (16 edges x 64 + pad)

  const int tid  = threadIdx.x;
  const int lane = tid & 63;
  const int wv   = tid >> 6;
  const int ln   = lane & 15;
  const int quad = lane >> 4;

  // ---- Stage W1^T, W2^T as bf16 into LDS ----
  for (int i = tid; i < 9216; i += TPB) {
    int n = i & 63, k = i >> 6;
    W1T[n * 168 + k] = bf16rne(W1[k * 64 + n]);
  }
  for (int i = tid; i < 1024; i += TPB) {            // zero-pad k in [144,160)
    int n = i & 63, k = 144 + (i >> 6);
    W1T[n * 168 + k] = 0;
  }
  for (int i = tid; i < 4096; i += TPB) {
    int n = i & 63, k = i >> 6;
    W2T[n * 72 + k] = bf16rne(W2[k * 64 + n]);
  }
  __syncthreads();   // the ONLY block barrier

  // ---- Per-lane n-indexed params (n = ln + 16*jt) ----
  float b1v[4], g1v[4], be1v[4], b2v[4], g2v[4], be2v[4], W3v[4];
  #pragma unroll
  for (int jt = 0; jt < 4; ++jt) {
    int n = ln + 16 * jt;
    b1v[jt] = b1[n];  g1v[jt] = g1[n];  be1v[jt] = be1[n];
    b2v[jt] = b2[n];  g2v[jt] = g2[n];  be2v[jt] = be2[n];
    W3v[jt] = W3[n];
  }
  const float b3s = b3[0];

  // int64-vs-int32 index sniff (validated rounds 3-6)
  const bool idx64 = (__ballot(ei[2 * lane + 1] == 0) == ~0ull);

  // ---- Prefetched indices for the first tile ----
  int sI[4], dI[4], eC[4];
  {
    const int ebase = blockIdx.x * 256 + wv * 64;
    #pragma unroll
    for (int mt = 0; mt < 4; ++mt) {
      int el = ebase + mt * 16 + ln;
      int ec = el < E ? el : E - 1;
      eC[mt] = ec;
      if (idx64) { sI[mt] = ei[2 * ec]; dI[mt] = ei[2 * (E + ec)]; }
      else       { sI[mt] = ei[ec];     dI[mt] = ei[E + ec]; }
    }
  }

  for (int tile = blockIdx.x; tile < ntiles; tile += gridDim.x) {
    const int ebase = tile * 256 + wv * 64;

    // ---- Batch gather: all 40 loads issued together, cvt by arrival ----
    short8 afr[4][5];
    #pragma unroll
    for (int mt = 0; mt < 4; ++mt) {
      const float* sp = nf + (size_t)sI[mt] * 64 + quad * 8;
      const float* dp = nf + (size_t)dI[mt] * 64 + quad * 8;
      const float* ap = ea + (size_t)eC[mt] * 16 + (quad & 1) * 8;
      f32x4 c0 = *(const f32x4*)sp;        f32x4 c1 = *(const f32x4*)(sp + 4);
      f32x4 c2 = *(const f32x4*)(sp + 32); f32x4 c3 = *(const f32x4*)(sp + 36);
      f32x4 c4 = *(const f32x4*)dp;        f32x4 c5 = *(const f32x4*)(dp + 4);
      f32x4 c6 = *(const f32x4*)(dp + 32); f32x4 c7 = *(const f32x4*)(dp + 36);
      f32x4 c8 = *(const f32x4*)ap;        f32x4 c9 = *(const f32x4*)(ap + 4);
      afr[mt][0] = cvt8(c0, c1);
      afr[mt][1] = cvt8(c2, c3);
      afr[mt][2] = cvt8(c4, c5);
      afr[mt][3] = cvt8(c6, c7);
      afr[mt][4] = cvt8(c8, c9);   // k>=144 lanes: B rows are zero, value moot
    }

    // ---- Layer 1: 80 MFMAs (bias pre-folded into acc init) ----
    f32x4 acc[4][4];                       // [mt][jt]
    #pragma unroll
    for (int mt = 0; mt < 4; ++mt)
      #pragma unroll
      for (int jt = 0; jt < 4; ++jt) acc[mt][jt] = (f32x4)(b1v[jt]);

    #pragma unroll
    for (int t = 0; t < 5; ++t)
      #pragma unroll
      for (int jt = 0; jt < 4; ++jt) {
        short8 bfr = *(const short8*)&W1T[(jt * 16 + ln) * 168 + t * 32 + quad * 8];
        #pragma unroll
        for (int mt = 0; mt < 4; ++mt)
          acc[mt][jt] = __builtin_amdgcn_mfma_f32_16x16x32_bf16(
              afr[mt][t], bfr, acc[mt][jt], 0, 0, 0);
      }

    // ---- Prefetch next tile's indices (latency hides behind epilogue) ----
    {
      int ntile = tile + gridDim.x;
      if (ntile < ntiles) {
        const int nb = ntile * 256 + wv * 64;
        #pragma unroll
        for (int mt = 0; mt < 4; ++mt) {
          int el = nb + mt * 16 + ln;
          int ec = el < E ? el : E - 1;
          eC[mt] = ec;
          if (idx64) { sI[mt] = ei[2 * ec]; dI[mt] = ei[2 * (E + ec)]; }
          else       { sI[mt] = ei[ec];     dI[mt] = ei[E + ec]; }
        }
      }
    }

    // ---- Epilogue per mt (wave-private; DPP reductions, no block barriers) --
    #pragma unroll
    for (int mt = 0; mt < 4; ++mt) {
      f32x4 sv = acc[mt][0] + acc[mt][1] + acc[mt][2] + acc[mt][3];
      f32x4 qv = acc[mt][0] * acc[mt][0] + acc[mt][1] * acc[mt][1]
               + acc[mt][2] * acc[mt][2] + acc[mt][3] * acc[mt][3];
      redsum16(sv);
      redsum16(qv);
      f32x4 mu  = sv * (1.f / 64.f);
      f32x4 var = qv * (1.f / 64.f) - mu * mu;
      f32x4 rs;
      rs[0] = rsqrtf(var[0] + LN_EPS); rs[1] = rsqrtf(var[1] + LN_EPS);
      rs[2] = rsqrtf(var[2] + LN_EPS); rs[3] = rsqrtf(var[3] + LN_EPS);

      #pragma unroll
      for (int jt = 0; jt < 4; ++jt)
        #pragma unroll
        for (int r = 0; r < 4; ++r) {
          float h = (acc[mt][jt][r] - mu[r]) * rs[r] * g1v[jt] + be1v[jt];
          h = fmaxf(h, NEG_SLOPE * h);
          HB[wv][(quad * 4 + r) * 72 + ln + 16 * jt] =
              (short)((fb(h) + 0x8000u) >> 16);
        }
      // wave-private handoff: DS is in-order per wave; drain writes then read
      asm volatile("s_waitcnt lgkmcnt(0)" ::: "memory");

      f32x4 acc2[4];
      #pragma unroll
      for (int jt = 0; jt < 4; ++jt) acc2[jt] = (f32x4)(b2v[jt]);
      #pragma unroll
      for (int t2 = 0; t2 < 2; ++t2) {
        short8 a2 = *(const short8*)&HB[wv][ln * 72 + t2 * 32 + quad * 8];
        #pragma unroll
        for (int jt = 0; jt < 4; ++jt) {
          short8 w2f = *(const short8*)&W2T[(jt * 16 + ln) * 72 + t2 * 32 + quad * 8];
          acc2[jt] = __builtin_amdgcn_mfma_f32_16x16x32_bf16(
              a2, w2f, acc2[jt], 0, 0, 0);
        }
      }

      f32x4 s2 = acc2[0] + acc2[1] + acc2[2] + acc2[3];
      f32x4 q2 = acc2[0] * acc2[0] + acc2[1] * acc2[1]
               + acc2[2] * acc2[2] + acc2[3] * acc2[3];
      redsum16(s2);
      redsum16(q2);
      f32x4 mu2  = s2 * (1.f / 64.f);
      f32x4 var2 = q2 * (1.f / 64.f) - mu2 * mu2;
      f32x4 rs2;
      rs2[0] = rsqrtf(var2[0] + LN_EPS); rs2[1] = rsqrtf(var2[1] + LN_EPS);
      rs2[2] = rsqrtf(var2[2] + LN_EPS); rs2[3] = rsqrtf(var2[3] + LN_EPS);

      f32x4 po = (f32x4)0.f;
      #pragma unroll
      for (int jt = 0; jt < 4; ++jt)
        #pragma unroll
        for (int r = 0; r < 4; ++r) {
          float h = (acc2[jt][r] - mu2[r]) * rs2[r] * g2v[jt] + be2v[jt];
          h = fmaxf(h, NEG_SLOPE * h);
          po[r] = fmaf(h, W3v[jt], po[r]);
        }
      redsum16(po);

      if (ln < 4) {       // lanes 0-3 of each quad store edges quad*4 + ln
        int e = ebase + mt * 16 + quad * 4 + ln;
        if (e < E) {
          float v = (ln == 0) ? po[0] : (ln == 1) ? po[1] : (ln == 2) ? po[2] : po[3];
          out[e] = v + b3s;
        }
      }
    }
  }
}

extern "C" void kernel_launch(void* const* d_in, const int* in_sizes, int n_in,
                              void* d_out, int out_size, void* d_ws, size_t ws_size,
                              hipStream_t stream) {
  const float* nf = (const float*)d_in[0];
  const int*   ei = (const int*)d_in[1];
  const float* ea = (const float*)d_in[2];

  const int E = out_size;
  const int ntiles = (E + 255) / 256;
  const int blocks = ntiles < 1024 ? ntiles : 1024;

  edge_mlp_mfma<<<blocks, TPB, 0, stream>>>(
      nf, ei, ea,
      (const float*)d_in[3],  (const float*)d_in[4],
      (const float*)d_in[5],  (const float*)d_in[6],
      (const float*)d_in[7],  (const float*)d_in[8],
      (const float*)d_in[9],  (const float*)d_in[10],
      (const float*)d_in[11], (const float*)d_in[12],
      (float*)d_out, E, ntiles);
}